// Round 4
// baseline (276.583 us; speedup 1.0000x reference)
//
#include <hip/hip_runtime.h>
#include <math.h>
#include <stdint.h>

#define D 4096
#define ROWS 8   // rows per wave, software-pipelined

typedef float f4 __attribute__((ext_vector_type(4)));

// Wave-private LDS slice: drain this wave's ds ops; no s_barrier needed.
__device__ __forceinline__ void lds_fence() {
    __asm__ volatile("s_waitcnt lgkmcnt(0)" ::: "memory");
}
// Wait until <=16 vmem ops outstanding. At row top the 16 newest are the
// previous row's stores; everything older (the prefetch DMA) must be done.
__device__ __forceinline__ void wait_vm16() {
    __asm__ volatile("s_waitcnt vmcnt(16)" ::: "memory");
}
__device__ __forceinline__ void wait_vm0() {
    __asm__ volatile("s_waitcnt vmcnt(0)" ::: "memory");
}

// Async DMA one 16 KB row into LDS: call q deposits lane l's 16 B at
// lds + q*1024B + l*16B  ->  lds[i] = row[i] contiguous. vmcnt-tracked.
__device__ __forceinline__ void async_row_load(const float* gsrc, float* ldsdst, int l) {
#pragma unroll
    for (int q = 0; q < 16; ++q) {
        __builtin_amdgcn_global_load_lds(
            (const __attribute__((address_space(1))) void*)(gsrc + q * 256 + 4 * l),
            (__attribute__((address_space(3))) void*)(ldsdst + q * 256),
            16, 0, 0);
    }
}

// In-register FWHT over the 6 bits of the register index (64 values/thread).
__device__ __forceinline__ void fwht64(float* v) {
#pragma unroll
    for (int h = 1; h < 64; h <<= 1) {
#pragma unroll
        for (int i = 0; i < 64; i += 2 * h) {
#pragma unroll
            for (int j = i; j < i + h; ++j) {
                const float a = v[j];
                const float b = v[j + h];
                v[j]     = a + b;
                v[j + h] = a - b;
            }
        }
    }
}

// g = g_mu + softplus(g_rho)*eps, pre-permuted to B-layout:
// gq[l*64 + k] = g[e], e = (l&3) | (k<<2) | ((l>>2)<<8)
__global__ void whvi_prep(const float* __restrict__ g_mu,
                          const float* __restrict__ g_rho,
                          const float* __restrict__ eps,
                          float* __restrict__ gq) {
    const int i = blockIdx.x * 256 + threadIdx.x;  // i = l*64 + k
    const int l = i >> 6, k = i & 63;
    const int e = (l & 3) | (k << 2) | ((l >> 2) << 8);
    const float r  = g_rho[e];
    const float sp = (r > 20.f) ? r : log1pf(expf(r));   // stable softplus
    gq[i] = g_mu[e] + sp * eps[e];
}

// One wave per block, ROWS rows per wave, ping-pong LDS prefetch.
// Layout A: lane l, reg r holds e = (r&3) | (l<<2) | ((r>>2)<<8)  (bits {0,1,8..11})
// Layout B: lane l, reg k holds e = (l&3) | (k<<2) | ((l>>2)<<8)  (bits {2..7})
// Transpose = swap lane<->reg. XOR swizzle word(r,l) = r*64 + (l ^ (r&28)):
// scatter side hits each bank 2x (free, m136), vector side is 8 words/bank
// (the b128 minimum). Scratch = the just-consumed ping-pong buffer, so LDS
// is exactly 2 x 16 KB.
__global__ void __launch_bounds__(64) whvi_main(
    const float* __restrict__ x,  const float* __restrict__ s1,
    const float* __restrict__ s2, const float* __restrict__ gq,
    const float* __restrict__ g_mu, const float* __restrict__ g_rho,
    const float* __restrict__ eps, float* __restrict__ out) {
    __shared__ alignas(16) float B[2][D];   // 32768 B
    const int l = threadIdx.x;
    const long long r0 = (long long)blockIdx.x * ROWS;
    const float* xbase = x + r0 * (long long)D;
    float v[64];

    async_row_load(xbase, B[0], l);   // prologue prefetch row 0
    wait_vm0();

    for (int i = 0; i < ROWS; ++i) {
        float* cur = B[i & 1];
        float* nxt = B[(i + 1) & 1];

        if (i) wait_vm16();           // prefetch(i) done; stores(i-1) may fly

        // issue prefetch of row i+1 (targets nxt, disjoint from cur)
        if (i + 1 < ROWS)
            async_row_load(xbase + (long long)(i + 1) * D, nxt, l);

        // ---- raw row, layout A, from LDS (b128) ----
#pragma unroll
        for (int q = 0; q < 16; ++q)
            *reinterpret_cast<f4*>(&v[4 * q]) =
                *reinterpret_cast<const f4*>(cur + q * 256 + 4 * l);

        // ---- * s2 (L1/L2-resident) ----
#pragma unroll
        for (int q = 0; q < 16; ++q) {
            const f4 s = *reinterpret_cast<const f4*>(s2 + q * 256 + 4 * l);
            v[4 * q + 0] *= s.x;
            v[4 * q + 1] *= s.y;
            v[4 * q + 2] *= s.z;
            v[4 * q + 3] *= s.w;
        }

        fwht64(v);                    // FWHT-1a: bits {0,1,8..11}

        // ---- transpose 1 (cur is now free scratch) ----
        lds_fence();
#pragma unroll
        for (int r = 0; r < 64; ++r)
            cur[r * 64 + (l ^ (r & 28))] = v[r];
        lds_fence();
#pragma unroll
        for (int t = 0; t < 16; ++t)
            *reinterpret_cast<f4*>(&v[4 * t]) =
                *reinterpret_cast<const f4*>(cur + l * 64 + ((4 * t) ^ (l & 28)));

        fwht64(v);                    // FWHT-1b: bits {2..7}  (FWHT #1 done)

        // ---- * g (pre-permuted, contiguous b128 per lane) ----
#pragma unroll
        for (int t = 0; t < 16; ++t) {
            const f4 g = *reinterpret_cast<const f4*>(gq + (l << 6) + 4 * t);
            v[4 * t + 0] *= g.x;
            v[4 * t + 1] *= g.y;
            v[4 * t + 2] *= g.z;
            v[4 * t + 3] *= g.w;
        }

        fwht64(v);                    // FWHT-2a: bits {2..7}

        // ---- transpose 2 (reverse: b128 write, b32 swizzled read) ----
        lds_fence();
#pragma unroll
        for (int t = 0; t < 16; ++t)
            *reinterpret_cast<f4*>(cur + l * 64 + ((4 * t) ^ (l & 28))) =
                *reinterpret_cast<const f4*>(&v[4 * t]);
        lds_fence();
#pragma unroll
        for (int r = 0; r < 64; ++r)
            v[r] = cur[r * 64 + (l ^ (r & 28))];

        fwht64(v);                    // FWHT-2b: bits {0,1,8..11}

        // ---- * s1, coalesced b128 store (fire-and-forget) ----
        float* outr = out + (r0 + i) * (long long)D;
#pragma unroll
        for (int q = 0; q < 16; ++q) {
            const f4 s = *reinterpret_cast<const f4*>(s1 + q * 256 + 4 * l);
            f4 o;
            o.x = v[4 * q + 0] * s.x;
            o.y = v[4 * q + 1] * s.y;
            o.z = v[4 * q + 2] * s.z;
            o.w = v[4 * q + 3] * s.w;
            *reinterpret_cast<f4*>(outr + q * 256 + 4 * l) = o;
        }
    }
}

extern "C" void kernel_launch(void* const* d_in, const int* in_sizes, int n_in,
                              void* d_out, int out_size, void* d_ws, size_t ws_size,
                              hipStream_t stream) {
    const float* x     = (const float*)d_in[0];
    const float* s1    = (const float*)d_in[1];
    const float* s2    = (const float*)d_in[2];
    const float* g_mu  = (const float*)d_in[3];
    const float* g_rho = (const float*)d_in[4];
    const float* eps   = (const float*)d_in[5];
    float* out = (float*)d_out;
    const int rows = in_sizes[0] / D;

    float* gq = (float*)d_ws;
    whvi_prep<<<D / 256, 256, 0, stream>>>(g_mu, g_rho, eps, gq);
    whvi_main<<<rows / ROWS, 64, 0, stream>>>(x, s1, s2, gq, g_mu, g_rho, eps, out);
}